// Round 5
// baseline (145.051 us; speedup 1.0000x reference)
//
#include <hip/hip_runtime.h>
#include <hip/hip_bf16.h>
#include <hip/hip_cooperative_groups.h>

#define B_ 8
#define S_ 2048
#define E_ 1024
#define H_ 64

typedef __attribute__((ext_vector_type(8))) short short8;
typedef __attribute__((ext_vector_type(4))) float f32x4;

__device__ __forceinline__ short f2bf(float f) {
    __hip_bfloat16 h = __float2bfloat16(f);
    return *(short*)&h;
}

__device__ __forceinline__ void g2l16(const void* g, void* l) {
    __builtin_amdgcn_global_load_lds(
        (const __attribute__((address_space(1))) void*)g,
        (__attribute__((address_space(3))) void*)l, 16, 0, 0);
}

// One fused cooperative kernel: phase0 W->Wt prep | sync | phase1 QKV | sync | phase2 attn.
// 256 blocks x 512 threads (8 waves), 80KB LDS -> all blocks resident.
__global__ __launch_bounds__(512, 1) void fused_attn(
    const float* __restrict__ x, const int* __restrict__ mask,
    const float* __restrict__ Wq, const float* __restrict__ bq,
    const float* __restrict__ Wk, const float* __restrict__ bk,
    const float* __restrict__ Wv, const float* __restrict__ bv,
    unsigned short* __restrict__ WtG, unsigned short* __restrict__ Q,
    unsigned short* __restrict__ K, unsigned short* __restrict__ Vt,
    float* __restrict__ out)
{
    __shared__ __align__(16) char pool[81920];
    int tid = threadIdx.x;
    int wave = tid >> 6, lane = tid & 63;
    int lo = lane & 15, hi = lane >> 4;
    int blk = blockIdx.x;

    // ---------------- phase 0: W [1024][64] f32 -> Wt [192][1024] bf16 ----------------
    {
        int idx = blk * 512 + tid;
        #pragma unroll
        for (int it = 0; it < 2; ++it) {
            if (idx < 192 * 1024) {
                int n = idx >> 10, k = idx & (E_ - 1);
                const float* W = (n < 64) ? Wq : (n < 128) ? Wk : Wv;
                WtG[idx] = (unsigned short)f2bf(W[k * 64 + (n & 63)]);
            }
            idx += 256 * 512;
        }
    }
    cooperative_groups::this_grid().sync();

    // ---------------- phase 1: QKV projection ----------------
    // Block = 64 rows. K-chunk = 64. LDS: x 2x16KB + Wt 2x24KB (both XOR-swizzled).
    // Wave (wm in 0..1: 32 rows, wn in 0..3: 48 cols = 3 nt-tiles). 192 MFMA/wave.
    {
        char* lds_x = pool;                 // [2][64][256B]
        char* lds_wt = pool + 32768;        // [2][192][128B]
        int wm = wave >> 2, wn = wave & 3;
        int rowbase = blk * 64;
        const char* xg = (const char*)x;
        const char* wtg = (const char*)WtG;
        int swz = (lo & 7) << 4;

        f32x4 acc[2][3];
        #pragma unroll
        for (int a = 0; a < 2; ++a)
            #pragma unroll
            for (int j = 0; j < 3; ++j) acc[a][j] = (f32x4){0.f, 0.f, 0.f, 0.f};

        #define STAGE(bb, kc)                                                          \
            {                                                                          \
                _Pragma("unroll")                                                      \
                for (int i = 0; i < 2; ++i) {                                          \
                    int r0 = wave * 8 + i * 4;                                         \
                    int r = r0 + (lane >> 4);                                          \
                    const char* src = xg + (size_t)(rowbase + r) * 4096 + (kc) * 256   \
                                      + (((lane & 15) * 16) ^ ((r & 7) << 4));         \
                    g2l16(src, lds_x + (bb) * 16384 + r0 * 256);                       \
                }                                                                      \
                _Pragma("unroll")                                                      \
                for (int i = 0; i < 3; ++i) {                                          \
                    int c0 = wave * 24 + i * 8;                                        \
                    int c = c0 + (lane >> 3);                                          \
                    const char* src = wtg + (size_t)c * 2048 + (kc) * 128              \
                                      + (((lane & 7) * 16) ^ ((c & 7) << 4));          \
                    g2l16(src, lds_wt + (bb) * 24576 + c0 * 128);                      \
                }                                                                      \
            }

        STAGE(0, 0);
        __syncthreads();

        for (int kc = 0; kc < 16; ++kc) {
            if (kc < 15) STAGE((kc + 1) & 1, kc + 1);
            const char* lx = lds_x + (kc & 1) * 16384;
            const char* lw = lds_wt + (kc & 1) * 24576;
            #pragma unroll
            for (int sub = 0; sub < 2; ++sub) {
                short8 bfr[3];
                #pragma unroll
                for (int j = 0; j < 3; ++j)
                    bfr[j] = *(const short8*)(lw + (wn * 48 + j * 16 + lo) * 128
                                              + ((sub * 64 + hi * 16) ^ swz));
                #pragma unroll
                for (int rt = 0; rt < 2; ++rt) {
                    int row = wm * 32 + rt * 16 + lo;
                    int off = (sub * 128 + hi * 32) ^ swz;
                    float4 a0 = *(const float4*)(lx + row * 256 + off);
                    float4 a1 = *(const float4*)(lx + row * 256 + (off ^ 16));
                    short8 af;
                    af[0] = f2bf(a0.x); af[1] = f2bf(a0.y); af[2] = f2bf(a0.z); af[3] = f2bf(a0.w);
                    af[4] = f2bf(a1.x); af[5] = f2bf(a1.y); af[6] = f2bf(a1.z); af[7] = f2bf(a1.w);
                    #pragma unroll
                    for (int j = 0; j < 3; ++j)
                        acc[rt][j] = __builtin_amdgcn_mfma_f32_16x16x32_bf16(af, bfr[j], acc[rt][j], 0, 0, 0);
                }
            }
            __syncthreads();
        }
        #undef STAGE

        #pragma unroll
        for (int rt = 0; rt < 2; ++rt) {
            #pragma unroll
            for (int j = 0; j < 3; ++j) {
                int nt = wn * 3 + j;
                int n = nt * 16 + lo;
                #pragma unroll
                for (int r = 0; r < 4; ++r) {
                    int row = rowbase + wm * 32 + rt * 16 + 4 * hi + r;
                    float v = acc[rt][j][r];
                    if (nt < 4) {
                        Q[(size_t)row * 64 + n] = (unsigned short)f2bf(v + bq[n]);
                    } else if (nt < 8) {
                        int h = n - 64;
                        K[(size_t)row * 64 + h] = (unsigned short)f2bf(v + bk[h]);
                    } else {
                        int h = n - 128;
                        int b = row >> 11, s = row & (S_ - 1);
                        Vt[((size_t)b * 64 + h) * S_ + s] = (unsigned short)f2bf(v + bv[h]);
                    }
                }
            }
        }
    }
    cooperative_groups::this_grid().sync();

    // ---------------- phase 2: flash attention ----------------
    // 512 tasks (b, 32-row qtile); block blk does (b0,qt0) and (b0,63-qt0) -> constant work.
    // 8 waves = 4 kv-chunks (wk) x 2 row-halves (wm2).
    {
        auto p_lds = (unsigned short(*)[16][72])pool;           // [8][16][72] = 18.4KB
        auto cm = (float(*)[4][64][25])(pool + 20480);          // [2][4][64][25] = 51.2KB
        int wk = wave >> 1, wm2 = wave & 1;
        int b0 = blk & 7, qt0 = blk >> 3;      // qt0 in [0,32)

        #pragma unroll
        for (int task = 0; task < 2; ++task) {
            int b = b0;
            int qt = task ? (63 - qt0) : qt0;
            int qrow0 = qt * 32 + wm2 * 16;

            const unsigned short* qp = Q + ((size_t)(b * S_ + qrow0 + lo)) * 64 + 8 * hi;
            short8 qf0 = *(const short8*)(qp);
            short8 qf1 = *(const short8*)(qp + 32);

            f32x4 o[4];
            float m[4], ls[4];
            #pragma unroll
            for (int i = 0; i < 4; ++i) {
                o[i] = (f32x4){0.f, 0.f, 0.f, 0.f};
                m[i] = -__builtin_inff();
                ls[i] = 0.f;
            }

            int nkt = (qt * 32 + 95) >> 6;
            int chunk = (nkt + 3) >> 2;
            int kt0 = wk * chunk;
            int kt1 = min(kt0 + chunk, nkt);

            for (int kt = kt0; kt < kt1; ++kt) {
                int kbase = kt * 64;
                int mv[4];
                #pragma unroll
                for (int nt = 0; nt < 4; ++nt) mv[nt] = mask[b * S_ + kbase + nt * 16 + lo];
                const unsigned short* vp = Vt + (size_t)b * 64 * S_ + kbase;
                short8 vf0[4];
                #pragma unroll
                for (int nt = 0; nt < 4; ++nt)
                    vf0[nt] = *(const short8*)(vp + (size_t)(nt * 16 + lo) * S_ + 8 * hi);

                f32x4 s[4];
                #pragma unroll
                for (int i = 0; i < 4; ++i) s[i] = (f32x4){0.f, 0.f, 0.f, 0.f};
                const unsigned short* kp = K + ((size_t)(b * S_ + kbase + lo)) * 64 + 8 * hi;
                #pragma unroll
                for (int nt = 0; nt < 4; ++nt) {
                    short8 kf0 = *(const short8*)(kp + (size_t)nt * 16 * 64);
                    short8 kf1 = *(const short8*)(kp + (size_t)nt * 16 * 64 + 32);
                    s[nt] = __builtin_amdgcn_mfma_f32_16x16x32_bf16(qf0, kf0, s[nt], 0, 0, 0);
                    s[nt] = __builtin_amdgcn_mfma_f32_16x16x32_bf16(qf1, kf1, s[nt], 0, 0, 0);
                }

                float rmax[4];
                #pragma unroll
                for (int r = 0; r < 4; ++r) rmax[r] = -__builtin_inff();
                #pragma unroll
                for (int nt = 0; nt < 4; ++nt) {
                    int kpos = kbase + nt * 16 + lo;
                    #pragma unroll
                    for (int r = 0; r < 4; ++r) {
                        int qpos = qrow0 + 4 * hi + r;
                        float v = s[nt][r] * 0.125f;
                        bool ok = (mv[nt] != 0) && (kpos <= qpos);
                        v = ok ? v : -__builtin_inff();
                        s[nt][r] = v;
                        rmax[r] = fmaxf(rmax[r], v);
                    }
                }
                #pragma unroll
                for (int r = 0; r < 4; ++r) {
                    rmax[r] = fmaxf(rmax[r], __shfl_xor(rmax[r], 1));
                    rmax[r] = fmaxf(rmax[r], __shfl_xor(rmax[r], 2));
                    rmax[r] = fmaxf(rmax[r], __shfl_xor(rmax[r], 4));
                    rmax[r] = fmaxf(rmax[r], __shfl_xor(rmax[r], 8));
                }
                float mneff[4], sc[4];
                #pragma unroll
                for (int r = 0; r < 4; ++r) {
                    float mn = fmaxf(m[r], rmax[r]);
                    bool dead = (mn == -__builtin_inff());
                    mneff[r] = dead ? 0.f : mn;
                    sc[r] = __expf(m[r] - mneff[r]);
                    m[r] = dead ? m[r] : mn;
                }
                float ps[4] = {0.f, 0.f, 0.f, 0.f};
                #pragma unroll
                for (int nt = 0; nt < 4; ++nt) {
                    #pragma unroll
                    for (int r = 0; r < 4; ++r) {
                        float p = __expf(s[nt][r] - mneff[r]);
                        ps[r] += p;
                        p_lds[wave][4 * hi + r][nt * 16 + lo] = (unsigned short)f2bf(p);
                    }
                }
                #pragma unroll
                for (int r = 0; r < 4; ++r) {
                    ps[r] += __shfl_xor(ps[r], 1);
                    ps[r] += __shfl_xor(ps[r], 2);
                    ps[r] += __shfl_xor(ps[r], 4);
                    ps[r] += __shfl_xor(ps[r], 8);
                    ls[r] = ls[r] * sc[r] + ps[r];
                }
                #pragma unroll
                for (int nt = 0; nt < 4; ++nt)
                    #pragma unroll
                    for (int r = 0; r < 4; ++r) o[nt][r] *= sc[r];

                {
                    short8 pf = *(const short8*)&p_lds[wave][lo][8 * hi];
                    #pragma unroll
                    for (int nt = 0; nt < 4; ++nt)
                        o[nt] = __builtin_amdgcn_mfma_f32_16x16x32_bf16(pf, vf0[nt], o[nt], 0, 0, 0);
                }
                {
                    short8 pf = *(const short8*)&p_lds[wave][lo][32 + 8 * hi];
                    #pragma unroll
                    for (int nt = 0; nt < 4; ++nt) {
                        short8 vf = *(const short8*)(vp + (size_t)(nt * 16 + lo) * S_ + 32 + 8 * hi);
                        o[nt] = __builtin_amdgcn_mfma_f32_16x16x32_bf16(pf, vf, o[nt], 0, 0, 0);
                    }
                }
            }

            // partials -> LDS: [0..3]=m, [4..7]=l, [8..23]=o
            #pragma unroll
            for (int r = 0; r < 4; ++r) {
                cm[wm2][wk][lane][r] = m[r];
                cm[wm2][wk][lane][4 + r] = ls[r];
            }
            #pragma unroll
            for (int nt = 0; nt < 4; ++nt)
                #pragma unroll
                for (int r = 0; r < 4; ++r)
                    cm[wm2][wk][lane][8 + nt * 4 + r] = o[nt][r];
            __syncthreads();

            // combine: wave (wm2, wk) produces output cols [wk*16, wk*16+16)
            #pragma unroll
            for (int r = 0; r < 4; ++r) {
                float mg = cm[wm2][0][lane][r];
                #pragma unroll
                for (int w2 = 1; w2 < 4; ++w2) mg = fmaxf(mg, cm[wm2][w2][lane][r]);
                float mge = (mg == -__builtin_inff()) ? 0.f : mg;
                float suml = 0.f, og = 0.f;
                #pragma unroll
                for (int w2 = 0; w2 < 4; ++w2) {
                    float e = __expf(cm[wm2][w2][lane][r] - mge);
                    suml += cm[wm2][w2][lane][4 + r] * e;
                    og += cm[wm2][w2][lane][8 + wk * 4 + r] * e;
                }
                int qpos = qrow0 + 4 * hi + r;
                out[((size_t)(b * S_ + qpos)) * 64 + wk * 16 + lo] =
                    (suml > 0.f) ? og / suml : 0.f;
            }
            __syncthreads();
        }
    }
}

extern "C" void kernel_launch(void* const* d_in, const int* in_sizes, int n_in,
                              void* d_out, int out_size, void* d_ws, size_t ws_size,
                              hipStream_t stream) {
    const float* x   = (const float*)d_in[0];
    const int*   msk = (const int*)d_in[1];
    const float* Wq  = (const float*)d_in[2];
    const float* bq  = (const float*)d_in[3];
    const float* Wk  = (const float*)d_in[4];
    const float* bk  = (const float*)d_in[5];
    const float* Wv  = (const float*)d_in[6];
    const float* bv  = (const float*)d_in[7];
    float* outp = (float*)d_out;

    // ws: Wt bf16 384KB | Q bf16 2MB | K bf16 2MB | Vt bf16 2MB
    unsigned short* Wt = (unsigned short*)d_ws;
    unsigned short* Qb = (unsigned short*)((char*)d_ws + (1u << 19));
    unsigned short* Kb = (unsigned short*)((char*)d_ws + (1u << 19) + (1u << 21));
    unsigned short* Vt = (unsigned short*)((char*)d_ws + (1u << 19) + (2u << 21));

    void* args[] = {(void*)&x, (void*)&msk, (void*)&Wq, (void*)&bq, (void*)&Wk,
                    (void*)&bk, (void*)&Wv, (void*)&bv, (void*)&Wt, (void*)&Qb,
                    (void*)&Kb, (void*)&Vt, (void*)&outp};
    hipLaunchCooperativeKernel((void*)fused_attn, dim3(256), dim3(512), args, 0, stream);
}